// Round 3
// baseline (257.852 us; speedup 1.0000x reference)
//
#include <hip/hip_runtime.h>

namespace {
constexpr int kInCh  = 64;
constexpr int kOutCh = 64;
constexpr int kK     = 3;
constexpr int kFanIn = 8;
constexpr int kH     = 1024;
constexpr int kTile  = 256;          // h-positions per block (doubled: in-flight bytes fix)
constexpr int kRow   = kTile + 8;    // LDS row: 4-float halo each side, float4-aligned
constexpr int kBlk   = 512;          // 8 waves
constexpr int kHB    = kH / kTile;   // 4 h-tiles per batch row
}

struct Tap { int off; float w; };    // off = BYTE offset into sm

// input fake-quant, INTEGER-valued result in [-128,127]. The *0.0625 scale is
// folded into the tap weight (VERIFIED round 2, absmax=0.0: pow2 scale, fmaf
// fuses the product — (w*2^-4)*q bit-identical to w*(q*2^-4); chain unchanged).
__device__ __forceinline__ float quant_in_i(float v) {
    float q = rintf(v * 16.0f);
    q = fmaxf(q, -128.0f);
    return fminf(q, 127.0f);
}

// output fake-quant in fp32 (ref conv+quant is fp32; *8 and *0.125 exact pow2)
__device__ __forceinline__ float quant_out(float v) {
    float q = rintf(v * 8.0f);
    q = fmaxf(q, -128.0f);
    q = fminf(q, 127.0f);
    return q * 0.125f;
}

// VERIFIED (absmax=0.0 rounds 1&2): reference == single fp32 FMA chain per output
// in (k-major, ci-minor) tap order. DO NOT change tap ordering or chain structure.
//
// ROUND 3: back to ONE-SHOT blocks (round-2 persistent loop serialized on
// vmcnt(0) draining output stores every tile: conv 84->95us, HBM 2.75->2.44TB/s).
// Baseline model: HBM needs ~22KB outstanding/CU; kTile=128 blocks held ~10KB
// -> measured 44% of peak, exactly latency-limited. kTile=256 doubles per-thread
// in-flight to 8 float4 (66KB/block), 2 blocks/CU. x loads issued FIRST; tap
// build (ballot compaction, fused) overlaps their latency; stage; barrier;
// compute 4 h per lane per output.
__global__ __launch_bounds__(kBlk, 4) void sparse_conv(
        const float* __restrict__ x,
        const float* __restrict__ weight,
        const float* __restrict__ mask,
        float*       __restrict__ out) {
    __shared__ float sm[kInCh * kRow];   // 67,584 B
    __shared__ Tap   tbl[kBlk];          //  4,096 B -> 70 KiB total, 2 blocks/CU

    const int t    = threadIdx.x;
    const int lane = t & 63;
    const int g    = __builtin_amdgcn_readfirstlane(t >> 6);   // wave index / o-group
    const int tau  = blockIdx.x;
    const int n    = tau >> 2;                  // kHB = 4
    const int h0   = (tau & (kHB - 1)) * kTile;
    const float* __restrict__ xn = x + (size_t)n * kInCh * kH + h0;

    // ---- 1. issue ALL x loads first (8 float4 body + halo): ~66KB/block in flight.
    //      Wave g loads rows {g, g+8, .., g+56}, col4 = lane -> 1KB contiguous/wave/row.
    float4 r[8];
    #pragma unroll
    for (int it = 0; it < 8; ++it)
        r[it] = reinterpret_cast<const float4*>(xn + (it * 8 + g) * kH)[lane];
    float4 rh = make_float4(0.f, 0.f, 0.f, 0.f);
    if (t < 64) {                 // left halo row t (only h0-1 ever read)
        if (h0 > 0) rh = *reinterpret_cast<const float4*>(xn + t * kH - 4);
    } else if (t < 128) {         // right halo row t-64 (only h0+kTile ever read)
        if (h0 + kTile < kH) rh = *reinterpret_cast<const float4*>(xn + (t - 64) * kH + kTile);
    }

    // ---- 2. build this wave's 64 taps (overlaps x-load latency). Rank order
    //      k-major / ci-minor — identical to verified ordering. tbl written and
    //      read by the SAME wave -> no barrier needed (lgkmcnt-ordered).
    {
        const unsigned long long low = (1ull << lane) - 1ull;
        #pragma unroll
        for (int oo = 0; oo < 8; ++oo) {
            const int o    = g * 8 + oo;
            const int base = (o * kInCh + lane) * kK;          // OIH storage, lane == ci
            const float m0 = mask[base + 0], m1 = mask[base + 1], m2 = mask[base + 2];
            const float w0 = weight[base + 0], w1 = weight[base + 1], w2 = weight[base + 2];
            const unsigned long long b0 = __ballot(m0 != 0.0f);
            const unsigned long long b1 = __ballot(m1 != 0.0f);
            const unsigned long long b2 = __ballot(m2 != 0.0f);
            const int n0 = __popcll(b0), n1 = __popcll(b1);
            // mask has exactly kFanIn ones per o => ranks cover 0..7 exactly
            if (m0 != 0.0f) { int rk = __popcll(b0 & low);
                tbl[o * kFanIn + rk].off = (lane * kRow + 3) * 4;
                tbl[o * kFanIn + rk].w   = w0 * m0 * 0.0625f; }
            if (m1 != 0.0f) { int rk = n0 + __popcll(b1 & low);
                tbl[o * kFanIn + rk].off = (lane * kRow + 4) * 4;
                tbl[o * kFanIn + rk].w   = w1 * m1 * 0.0625f; }
            if (m2 != 0.0f) { int rk = n0 + n1 + __popcll(b2 & low);
                tbl[o * kFanIn + rk].off = (lane * kRow + 5) * 4;
                tbl[o * kFanIn + rk].w   = w2 * m2 * 0.0625f; }
        }
    }
    // lane l holds tap (j = l&7) of output (g*8 + l>>3); broadcast via readlane
    const int vOff = tbl[t].off;
    const int vW   = __float_as_int(tbl[t].w);

    // ---- 3. stage (waits on x loads), quantize once on store ----
    #pragma unroll
    for (int it = 0; it < 8; ++it) {
        float4 q;
        q.x = quant_in_i(r[it].x); q.y = quant_in_i(r[it].y);
        q.z = quant_in_i(r[it].z); q.w = quant_in_i(r[it].w);
        reinterpret_cast<float4*>(&sm[(it * 8 + g) * kRow + 4])[lane] = q;
    }
    if (t < 64) {
        float4 q;
        q.x = quant_in_i(rh.x); q.y = quant_in_i(rh.y);
        q.z = quant_in_i(rh.z); q.w = quant_in_i(rh.w);
        *reinterpret_cast<float4*>(&sm[t * kRow]) = q;
    } else if (t < 128) {
        float4 q;
        q.x = quant_in_i(rh.x); q.y = quant_in_i(rh.y);
        q.z = quant_in_i(rh.z); q.w = quant_in_i(rh.w);
        *reinterpret_cast<float4*>(&sm[(t - 64) * kRow + 4 + kTile]) = q;
    }
    __syncthreads();

    // ---- 4. compute: wave g owns outputs g*8..g*8+7; lane does h in {i,i+64,i+128,i+192} ----
    const int i4 = lane << 2;                    // byte offset of lane's h within a row
    const char* smb = reinterpret_cast<const char*>(sm);
    float* __restrict__ outn = out + (size_t)n * kOutCh * kH + h0;

    #pragma unroll 2
    for (int oo = 0; oo < 8; ++oo) {
        const int o = g * 8 + oo;
        // Single sequential fp32 FMA chain per output element, j ascending
        // (verified order). 4 independent chains; ds_read2_b32 pairs
        // (offsets +0/+64 and +128/+192 dwords), stride-1 lanes, conflict-free.
        float a0 = 0.f, a1 = 0.f, a2 = 0.f, a3 = 0.f;
        #pragma unroll
        for (int j = 0; j < kFanIn; ++j) {
            const int l   = oo * 8 + j;                               // uniform
            const int off = __builtin_amdgcn_readlane(vOff, l);       // SGPR
            const float w = __int_as_float(__builtin_amdgcn_readlane(vW, l));
            const char* p = smb + off + i4;
            a0 = fmaf(w, *reinterpret_cast<const float*>(p      ), a0);
            a1 = fmaf(w, *reinterpret_cast<const float*>(p + 256), a1);
            a2 = fmaf(w, *reinterpret_cast<const float*>(p + 512), a2);
            a3 = fmaf(w, *reinterpret_cast<const float*>(p + 768), a3);
        }
        outn[o * kH + lane]       = quant_out(a0);
        outn[o * kH + lane +  64] = quant_out(a1);
        outn[o * kH + lane + 128] = quant_out(a2);
        outn[o * kH + lane + 192] = quant_out(a3);
    }
}

extern "C" void kernel_launch(void* const* d_in, const int* in_sizes, int n_in,
                              void* d_out, int out_size, void* d_ws, size_t ws_size,
                              hipStream_t stream) {
    const float* x      = (const float*)d_in[0];
    const float* weight = (const float*)d_in[1];
    const float* mask   = (const float*)d_in[2];
    float* out = (float*)d_out;

    const int nBatch = in_sizes[0] / (kInCh * kH);   // 512
    const int grid   = nBatch * kHB;                 // 2048 one-shot blocks

    sparse_conv<<<grid, kBlk, 0, stream>>>(x, weight, mask, out);
}

// Round 4
// 238.095 us; speedup vs baseline: 1.0830x; 1.0830x over previous
//
#include <hip/hip_runtime.h>

namespace {
constexpr int kInCh  = 64;
constexpr int kOutCh = 64;
constexpr int kK     = 3;
constexpr int kFanIn = 8;
constexpr int kH     = 1024;
constexpr int kTile  = 64;           // h-positions per block (small: maximize blocks/CU)
constexpr int kRow   = kTile + 8;    // 72 floats: [3]=x[h0-1], [4..67]=body, [68]=x[h0+64]
constexpr int kBlk   = 256;          // 4 waves; 8 blocks/CU (LDS+wave cap both hit 32 waves/CU)
constexpr int kHB    = kH / kTile;   // 16 h-tiles per batch row
}

struct Tap { int off; float w; };    // off = DWORD offset into sm

// input fake-quant, INTEGER-valued result in [-128,127]. The *0.0625 scale is
// folded into the tap weight (VERIFIED rounds 2-3, absmax=0.0: pow2 scale, fmaf
// fuses the product — (w*2^-4)*q bit-identical to w*(q*2^-4); chain unchanged).
__device__ __forceinline__ float quant_in_i(float v) {
    float q = rintf(v * 16.0f);
    q = fmaxf(q, -128.0f);
    return fminf(q, 127.0f);
}

// output fake-quant in fp32 (ref conv+quant is fp32; *8 and *0.125 exact pow2)
__device__ __forceinline__ float quant_out(float v) {
    float q = rintf(v * 8.0f);
    q = fmaxf(q, -128.0f);
    q = fminf(q, 127.0f);
    return q * 0.125f;
}

// VERIFIED (absmax=0.0 rounds 1-3): reference == single fp32 FMA chain per output
// in (k-major, ci-minor) tap order. DO NOT change tap ordering or chain structure.
//
// Parallel stable compaction: 64 blocks (one per o) x 192 threads (one per key
// j = k*64 + ci). Rank = count of nonzero keys < j, via per-wave ballots.
__global__ void prep_taps(const float* __restrict__ weight,
                          const float* __restrict__ mask,
                          Tap* __restrict__ taps) {
    __shared__ unsigned long long bal[3];
    const int o    = blockIdx.x;
    const int j    = threadIdx.x;        // key: k*64 + ci  (wave index == k)
    const int k    = j >> 6;
    const int ci   = j & 63;
    const int idx  = (o * kInCh + ci) * kK + k;   // OIH storage

    const float m = mask[idx];
    const unsigned long long b = __ballot(m != 0.0f);
    if (ci == 0) bal[k] = b;
    __syncthreads();

    const unsigned long long lower = b & ((1ull << ci) - 1ull);
    int rank = __popcll(lower);
    #pragma unroll
    for (int w = 0; w < kK; ++w) if (w < k) rank += __popcll(bal[w]);

    if (m != 0.0f && rank < kFanIn) {
        taps[o * kFanIn + rank].off = ci * kRow + k + 3;       // dword offset
        taps[o * kFanIn + rank].w   = weight[idx] * m * 0.0625f;
    }
    // zero-pad slots beyond the total nonzero count (ws is poisoned 0xAA)
    int total = __popcll(bal[0]) + __popcll(bal[1]) + __popcll(bal[2]);
    if (j >= total && j < kFanIn) {
        taps[o * kFanIn + j].off = 3;
        taps[o * kFanIn + j].w   = 0.0f;
    }
}

// ROUND 4: convoy-breaking via MAX independent blocks/CU. Evidence: R1 (4 blk/CU)
// 84us/HBM 44%; R2 persistent (vmcnt drain) 95us; R3 fat tiles (2 blk/CU) 106us
// — concurrency down => worse. Resource totals are tiny (VALU ~10us, LDS ~7us,
// HBM floor ~36us); the 84us is per-CU phase convoy (all resident blocks load
// together -> HBM-serial -> all compute together -> HBM idle). block=256/kTile=64
// doubles blocks/CU to 8 (LDS 18.4KB, 32 waves — both caps exactly): more
// independently-phased blocks keep HBM busy during other blocks' compute.
// Taps via separate prep kernel + uniform s_loads (hot kernel lean; R0 vs R1
// proved s_load == readlane == neutral, so pick the simplest).
__global__ __launch_bounds__(kBlk, 8) void sparse_conv(
        const float* __restrict__ x,
        const Tap*   __restrict__ taps,
        float*       __restrict__ out) {
    __shared__ float sm[kInCh * kRow];   // 18,432 B -> 8 blocks/CU

    const int t    = threadIdx.x;
    const int lane = t & 63;
    const int g    = __builtin_amdgcn_readfirstlane(t >> 6);   // wave = o-group (0..3)
    const int h0   = blockIdx.x * kTile;
    const int n    = blockIdx.y;
    const float* __restrict__ xn = x + (size_t)n * kInCh * kH + h0;

    // ---- 1. issue all x loads (4 float4 body/thread + 1-float halos) ----
    float4 r[4];
    #pragma unroll
    for (int it = 0; it < 4; ++it) {
        const int f  = it * kBlk + t;
        const int ci = f >> 4;           // 16 float4 per row
        const int c4 = f & 15;
        r[it] = reinterpret_cast<const float4*>(xn + ci * kH)[c4];
    }
    float hv = 0.f;
    if (t < 64) {                        // left halo row t: only x[h0-1] is ever read
        if (h0 > 0) hv = xn[t * kH - 1];
    } else if (t < 128) {                // right halo row t-64: only x[h0+kTile]
        if (h0 + kTile < kH) hv = xn[(t - 64) * kH + kTile];
    }

    // ---- 2. stage, quantize once on store ----
    #pragma unroll
    for (int it = 0; it < 4; ++it) {
        const int f  = it * kBlk + t;
        const int ci = f >> 4;
        const int c4 = f & 15;
        float4 q;
        q.x = quant_in_i(r[it].x); q.y = quant_in_i(r[it].y);
        q.z = quant_in_i(r[it].z); q.w = quant_in_i(r[it].w);
        reinterpret_cast<float4*>(&sm[ci * kRow + 4])[c4] = q;   // 16B-aligned
    }
    if (t < 64) {
        sm[t * kRow + 3] = quant_in_i(hv);
    } else if (t < 128) {
        sm[(t - 64) * kRow + 4 + kTile] = quant_in_i(hv);
    }
    __syncthreads();

    // ---- 3. compute: wave g owns outputs g*16..g*16+15; lane does h = h0+lane ----
    float* __restrict__ outn = out + (size_t)n * kOutCh * kH + h0;

    #pragma unroll 4
    for (int oo = 0; oo < 16; ++oo) {
        const int o = g * 16 + oo;
        const Tap* __restrict__ tp = taps + o * kFanIn;   // uniform -> s_load_dwordx2
        // Single sequential fp32 FMA chain, j ascending (verified order).
        // ds_read_b32, stride-1 lanes -> 2 lanes/bank = conflict-free.
        float acc = 0.f;
        #pragma unroll
        for (int j = 0; j < kFanIn; ++j) {
            acc = fmaf(tp[j].w, sm[tp[j].off + lane], acc);
        }
        outn[o * kH + lane] = quant_out(acc);
    }
}

extern "C" void kernel_launch(void* const* d_in, const int* in_sizes, int n_in,
                              void* d_out, int out_size, void* d_ws, size_t ws_size,
                              hipStream_t stream) {
    const float* x      = (const float*)d_in[0];
    const float* weight = (const float*)d_in[1];
    const float* mask   = (const float*)d_in[2];
    float* out = (float*)d_out;
    Tap* taps = (Tap*)d_ws;   // 64*8*8 B = 4 KiB of workspace

    const int nBatch = in_sizes[0] / (kInCh * kH);   // 512

    prep_taps<<<kOutCh, kInCh * kK, 0, stream>>>(weight, mask, taps);
    dim3 grid(kHB, nBatch);                          // (16, 512) one-shot blocks
    sparse_conv<<<grid, kBlk, 0, stream>>>(x, taps, out);
}